// Round 5
// baseline (3044.887 us; speedup 1.0000x reference)
//
#include <hip/hip_runtime.h>
#include <hip/hip_bf16.h>
#include <math.h>

// ---------------------------------------------------------------------------
// Bayesian LSTM, MI355X persistent-kernel design, round 7.
//   R7 changes (driven by R6 counters: conflicts invariant at 1.2e8, VGPR=112):
//   - W' IN REGISTERS: 64 main + 8 x-part bf16x8 fragments per thread
//     (288 VGPR), loaded once from global at init. K-loop has ZERO LDS
//     reads; LDS shrinks to the 8.7KB gbuf. Removes the ~2-3k cyc/step
//     inherent ds_read_b128 cost + all W'-read bank conflicts.
//   - h staging areg[16] x 2 halves (64 VGPR) to fit ~400 total budget.
//   - poll de-contention: ushort flags (64 x 2B = ONE line per group);
//     ONLY wave 0 polls (s_sleep(2)); waves 1-3 park at release barrier.
//     R6 had 4 waves x 256 blocks polling 16 lines -> MALL hot-line storm.
//   - keep: epoch ring P<=16 + one acquire fence per P steps; packed h
//     slot [64 blk][32 b][16 col]; h-store -> vmcnt(0) -> sync -> flag;
//     ys + x-part MFMA in the barrier shadow.
// ---------------------------------------------------------------------------

#define T_STEPS 384
#define HID 1024
#define KTOT 1152            // HID + IN

// ws layout (bytes)
#define WS_WG    0ull                  // 4096*1152*2 = 9437184
#define WS_XBF   9437184ull            // 384*128*128*2 = 12582912
#define WS_BSUM  22020096ull           // 4096*4
#define WS_ACC   22036480ull           // 8 doubles
#define WS_FLAGS 22036544ull           // 4 groups * 64 * 2B = 512
#define WS_HBUF  22037568ull           // 4 groups * P slots * 64KB
#define WS_ZERO_LEN 1088ull            // accd + flags (exactly up to HBUF)

#define OUT_HN 50331648ull
#define OUT_CN 50462720ull
#define OUT_KL 50593792ull

typedef __bf16 bf16_t;
typedef bf16_t bf16x8 __attribute__((ext_vector_type(8)));
typedef float f32x4 __attribute__((ext_vector_type(4)));

__device__ __forceinline__ unsigned short f2bf(float f) {
  unsigned int u = __float_as_uint(f);
  u += 0x7fffu + ((u >> 16) & 1u);          // round-to-nearest-even
  return (unsigned short)(u >> 16);
}
__device__ __forceinline__ bf16x8 ld_bf16x8(const void* p) {
  union { uint4 u; bf16x8 v; } c;
  c.u = *(const uint4*)p;
  return c.v;
}
__device__ __forceinline__ bf16x8 u4bf(uint4 u) {
  union { uint4 u; bf16x8 v; } c;
  c.u = u;
  return c.v;
}
__device__ __forceinline__ float sigm(float x) { return 1.f / (1.f + __expf(-x)); }
__device__ __forceinline__ float tanh_fast(float x) {
  float ax = fabsf(x);
  float e = __expf(-2.f * ax);
  float t = (1.f - e) / (1.f + e);
  return copysignf(t, x);
}

// ---------------------------------------------------------------------------
__global__ __launch_bounds__(256) void prep_kernel(
    const float* __restrict__ x,
    const float* __restrict__ wim, const float* __restrict__ wir, const float* __restrict__ wie,
    const float* __restrict__ whm, const float* __restrict__ whr, const float* __restrict__ whe,
    const float* __restrict__ bim, const float* __restrict__ bir, const float* __restrict__ bie,
    const float* __restrict__ bhm, const float* __restrict__ bhr, const float* __restrict__ bhe,
    unsigned short* __restrict__ Wg, unsigned short* __restrict__ xbf,
    float* __restrict__ bsum, double* __restrict__ accd)
{
  const int NHH = 4194304, NIH = 524288, NB = 4096, NX = 6291456;
  const int NTOT = NHH + NIH + NB + NX;
  double a0=0,a1=0,a2=0,a3=0,a4=0,a5=0,a6=0,a7=0;
  int stride = gridDim.x * blockDim.x;
  for (int i = blockIdx.x * blockDim.x + threadIdx.x; i < NTOT; i += stride) {
    if (i < NHH) {                                   // w_hh -> W'[g][0:1024]
      int g = i >> 10, k = i & 1023;
      float sg = log1pf(expf(whr[i])) + 1e-5f;
      float eps = whe[i];
      float w = fmaf(sg, eps, whm[i]);
      Wg[(size_t)g * KTOT + k] = f2bf(w);
      a2 += (double)(logf(sg) + 0.5f * eps * eps);
      a3 += (double)w * (double)w;
    } else if (i < NHH + NIH) {                      // w_ih -> W'[g][1024:1152]
      int j = i - NHH;
      int g = j >> 7, k = j & 127;
      float sg = log1pf(expf(wir[j])) + 1e-5f;
      float eps = wie[j];
      float w = fmaf(sg, eps, wim[j]);
      Wg[(size_t)g * KTOT + HID + k] = f2bf(w);
      a0 += (double)(logf(sg) + 0.5f * eps * eps);
      a1 += (double)w * (double)w;
    } else if (i < NHH + NIH + NB) {                 // biases
      int k = i - NHH - NIH;
      float sg1 = log1pf(expf(bir[k])) + 1e-5f;
      float e1 = bie[k];
      float w1 = fmaf(sg1, e1, bim[k]);
      a4 += (double)(logf(sg1) + 0.5f * e1 * e1);
      a5 += (double)w1 * (double)w1;
      float sg2 = log1pf(expf(bhr[k])) + 1e-5f;
      float e2 = bhe[k];
      float w2 = fmaf(sg2, e2, bhm[k]);
      a6 += (double)(logf(sg2) + 0.5f * e2 * e2);
      a7 += (double)w2 * (double)w2;
      bsum[k] = w1 + w2;
    } else {                                         // x -> bf16
      int k = i - NHH - NIH - NB;
      xbf[k] = f2bf(x[k]);
    }
  }
  double v[8] = {a0,a1,a2,a3,a4,a5,a6,a7};
  int lane = threadIdx.x & 63, wave = threadIdx.x >> 6;
  __shared__ double red[4][8];
  #pragma unroll
  for (int q = 0; q < 8; ++q) {
    double t = v[q];
    #pragma unroll
    for (int o = 32; o > 0; o >>= 1) t += __shfl_down(t, o, 64);
    if (lane == 0) red[wave][q] = t;
  }
  __syncthreads();
  if (threadIdx.x == 0) {
    #pragma unroll
    for (int q = 0; q < 8; ++q) {
      double s = red[0][q] + red[1][q] + red[2][q] + red[3][q];
      atomicAdd(&accd[q], s);
    }
  }
}

// ---------------------------------------------------------------------------
__global__ __launch_bounds__(256, 1) void lstm_kernel(
    const unsigned short* __restrict__ Wg, const unsigned short* __restrict__ xbf,
    const float* __restrict__ bsum, unsigned short* __restrict__ hbuf,
    unsigned short* __restrict__ flags, const double* __restrict__ accd,
    float* __restrict__ out, int P)
{
  __shared__ float gbuf[32 * 68];                    // 8704 B (only LDS used)
  const int tid = threadIdx.x, gid = blockIdx.x;
  const int group = gid >> 6, idx = gid & 63, j0 = idx * 16;

  if (gid == 0 && tid == 0) {
    // KL finalize (logsumexp over tensor-level sums)
    const double L2PI = 1.8378770664093453;
    const double LN_PI = -0.28768207245178085;    // ln 0.75
    const double LN_1MPI = -1.3862943611198906;   // ln 0.25
    const double INV2S1 = 3.694528049465325;      // e^2/2
    const double INV2S2 = 601302.1420823884;      // e^14/2
    double Ns[4] = {524288.0, 4194304.0, 4096.0, 4096.0};
    double kl = 0.0;
    #pragma unroll
    for (int tq = 0; tq < 4; ++tq) {
      double post_acc = accd[2*tq], w2 = accd[2*tq+1];
      double N = Ns[tq];
      double post = -0.5 * N * L2PI - post_acc;
      double m1 = -0.5 * N * L2PI + N * 1.0 - w2 * INV2S1 + LN_PI;
      double m2 = -0.5 * N * L2PI + N * 7.0 - w2 * INV2S2 + LN_1MPI;
      double mx = fmax(m1, m2), mn = fmin(m1, m2);
      double lse = mx + log1p(exp(mn - mx));
      kl += post - lse;
    }
    out[OUT_KL] = (float)kl;
  }

  const int lane = tid & 63, wave = tid >> 6;
  const int lq = lane >> 4, ln = lane & 15;
  const int mt = wave >> 1;                       // M-tile (batch half)
  const int nt0 = (wave & 1) * 2, nt1 = nt0 + 1;  // two N-tiles (gate pairs)
  const int arow = mt * 16 + ln;                  // batch-in-group for A-frag

  // ---- W' fragments resident in REGISTERS (loaded once) ----
  // B row for gate p, out-col j0+ln; fragment kk covers k = 32kk+8lq..+8.
  const unsigned short* r0 = Wg + (size_t)(nt0 * 1024 + j0 + ln) * KTOT + 8 * lq;
  const unsigned short* r1 = Wg + (size_t)(nt1 * 1024 + j0 + ln) * KTOT + 8 * lq;
  bf16x8 B0[32], B1[32], BX0[4], BX1[4];
  #pragma unroll
  for (int kk = 0; kk < 32; ++kk) {
    B0[kk] = ld_bf16x8(r0 + 32 * kk);
    B1[kk] = ld_bf16x8(r1 + 32 * kk);
  }
  #pragma unroll
  for (int kk = 0; kk < 4; ++kk) {
    BX0[kk] = ld_bf16x8(r0 + HID + 32 * kk);
    BX1[kk] = ld_bf16x8(r1 + HID + 32 * kk);
  }

  unsigned short* hgrp = hbuf + (size_t)group * (size_t)P * 32768;
  const unsigned short* xrow = xbf + (size_t)(group * 32 + arow) * 128 + 8 * lq;
  unsigned short* fl = flags + group * 64;
  // consumer A-frag base into a packed slot [64 blk][32 b][16 col] (shorts)
  const int hbase = (lq >> 1) * 512 + arow * 16 + 8 * (lq & 1);

  // nonlinearity mapping: thread -> (batch b, 2 consecutive j's)
  const int b = tid >> 3, jj0 = (tid & 7) * 2;
  const float2 bi0 = *(const float2*)&bsum[j0 + jj0];
  const float2 bi1 = *(const float2*)&bsum[1024 + j0 + jj0];
  const float2 bi2 = *(const float2*)&bsum[2048 + j0 + jj0];
  const float2 bi3 = *(const float2*)&bsum[3072 + j0 + jj0];
  float c0 = 0.f, c1 = 0.f;

  // prologue: x-part of step 0 (h_{-1}=0 -> h-GEMM skipped at t=0)
  f32x4 acc0 = {0.f,0.f,0.f,0.f}, acc1 = {0.f,0.f,0.f,0.f};
  #pragma unroll
  for (int kk = 0; kk < 4; ++kk) {
    bf16x8 a = ld_bf16x8(xrow + 32 * kk);
    acc0 = __builtin_amdgcn_mfma_f32_16x16x32_bf16(a, BX0[kk], acc0, 0, 0, 0);
    acc1 = __builtin_amdgcn_mfma_f32_16x16x32_bf16(a, BX1[kk], acc1, 0, 0, 0);
  }

  for (int t = 0; t < T_STEPS; ++t) {
    if (t > 0) {
      // epoch boundary: one amortized acquire (cache inv) per P steps,
      // executed by ALL waves before their slot re-reads.
      if (((t - 1) & (P - 1)) == 0) {
        __builtin_amdgcn_fence(__ATOMIC_ACQUIRE, "agent");
        __builtin_amdgcn_sched_barrier(0);
      }
      const unsigned short* hr =
          hgrp + (size_t)((t - 1) & (P - 1)) * 32768 + hbase;
      f32x4 acc2 = {0.f,0.f,0.f,0.f}, acc3 = {0.f,0.f,0.f,0.f};
      uint4 areg[16];
      // half 1: stage 16 A-frags, then MFMA from register-resident B
      #pragma unroll
      for (int kk = 0; kk < 16; ++kk)
        areg[kk] = *(const uint4*)(hr + kk * 1024);
      __builtin_amdgcn_sched_barrier(0);
      #pragma unroll
      for (int kk = 0; kk < 16; kk += 2) {
        bf16x8 a0 = u4bf(areg[kk]);
        bf16x8 a1 = u4bf(areg[kk + 1]);
        acc0 = __builtin_amdgcn_mfma_f32_16x16x32_bf16(a0, B0[kk], acc0, 0, 0, 0);
        acc1 = __builtin_amdgcn_mfma_f32_16x16x32_bf16(a0, B1[kk], acc1, 0, 0, 0);
        acc2 = __builtin_amdgcn_mfma_f32_16x16x32_bf16(a1, B0[kk+1], acc2, 0, 0, 0);
        acc3 = __builtin_amdgcn_mfma_f32_16x16x32_bf16(a1, B1[kk+1], acc3, 0, 0, 0);
      }
      // half 2 (reuses areg slots; loads overlap half-1 MFMA tail)
      #pragma unroll
      for (int kk = 0; kk < 16; ++kk)
        areg[kk] = *(const uint4*)(hr + (16 + kk) * 1024);
      #pragma unroll
      for (int kk = 0; kk < 16; kk += 2) {
        bf16x8 a0 = u4bf(areg[kk]);
        bf16x8 a1 = u4bf(areg[kk + 1]);
        acc0 = __builtin_amdgcn_mfma_f32_16x16x32_bf16(a0, B0[16+kk], acc0, 0, 0, 0);
        acc1 = __builtin_amdgcn_mfma_f32_16x16x32_bf16(a0, B1[16+kk], acc1, 0, 0, 0);
        acc2 = __builtin_amdgcn_mfma_f32_16x16x32_bf16(a1, B0[17+kk], acc2, 0, 0, 0);
        acc3 = __builtin_amdgcn_mfma_f32_16x16x32_bf16(a1, B1[17+kk], acc3, 0, 0, 0);
      }
      acc0 += acc2;
      acc1 += acc3;
    }
    // C layout: col=lane&15 (gate row), row=(lane>>4)*4+r (batch)
    #pragma unroll
    for (int r = 0; r < 4; ++r) {
      int m = mt * 16 + lq * 4 + r;
      gbuf[m * 68 + nt0 * 16 + ln] = acc0[r];
      gbuf[m * 68 + nt1 * 16 + ln] = acc1[r];
    }
    __syncthreads();

    // gate nonlinearity: (b, jj0), (b, jj0+1); c-state in registers
    float2 gi = *(const float2*)&gbuf[b * 68 + jj0];
    float2 gf = *(const float2*)&gbuf[b * 68 + 16 + jj0];
    float2 gg = *(const float2*)&gbuf[b * 68 + 32 + jj0];
    float2 go = *(const float2*)&gbuf[b * 68 + 48 + jj0];
    float c0n = sigm(gf.x + bi1.x) * c0 + sigm(gi.x + bi0.x) * tanh_fast(gg.x + bi2.x);
    float c1n = sigm(gf.y + bi1.y) * c1 + sigm(gi.y + bi0.y) * tanh_fast(gg.y + bi2.y);
    float h0 = sigm(go.x + bi3.x) * tanh_fast(c0n);
    float h1 = sigm(go.y + bi3.y) * tanh_fast(c1n);
    c0 = c0n; c1 = c1n;
    const bool last_t = (t == T_STEPS - 1);

    if (!last_t) {
      // h feedback: packed slot chunk, addr = tid*4 -> perfectly coalesced
      unsigned int* hw32 = (unsigned int*)(hgrp + (size_t)(t & (P - 1)) * 32768);
      unsigned int pk = (unsigned)f2bf(h0) | ((unsigned)f2bf(h1) << 16);
      __hip_atomic_store(&hw32[idx * 256 + tid], pk,
                         __ATOMIC_RELAXED, __HIP_MEMORY_SCOPE_AGENT);
      // drain ONLY the h store (ys/x not yet issued) -> minimal pre-flag path
      asm volatile("s_waitcnt vmcnt(0)" ::: "memory");
      __syncthreads();                           // all waves' h drained
      if (tid == 0)
        __hip_atomic_store(&fl[idx], (unsigned short)(t + 1),
                           __ATOMIC_RELAXED, __HIP_MEMORY_SCOPE_AGENT);
    }

    // ---- barrier shadow: ys / hn / cn stores, then x-part of step t+1 ----
    {
      size_t bg = (size_t)(group * 32 + b);
      float2 hs = {h0, h1};
      *(float2*)&out[(size_t)t * 131072 + bg * 1024 + j0 + jj0] = hs;
      if (last_t) {
        *(float2*)&out[OUT_HN + bg * 1024 + j0 + jj0] = hs;
        float2 cs = {c0n, c1n};
        *(float2*)&out[OUT_CN + bg * 1024 + j0 + jj0] = cs;
      }
    }
    if (!last_t) {
      acc0 = (f32x4){0.f,0.f,0.f,0.f};
      acc1 = (f32x4){0.f,0.f,0.f,0.f};
      const unsigned short* xr = xrow + (size_t)(t + 1) * 16384;
      #pragma unroll
      for (int kk = 0; kk < 4; ++kk) {
        bf16x8 a = ld_bf16x8(xr + 32 * kk);
        acc0 = __builtin_amdgcn_mfma_f32_16x16x32_bf16(a, BX0[kk], acc0, 0, 0, 0);
        acc1 = __builtin_amdgcn_mfma_f32_16x16x32_bf16(a, BX1[kk], acc1, 0, 0, 0);
      }

      // flag barrier: ONLY wave 0 polls (one 128B line per group); waves
      // 1-3 park at the release syncthreads. 16x less MALL hot-line
      // traffic than R6's all-wave polling.
      if (wave == 0) {
        const unsigned short tgt = (unsigned short)(t + 1);
        unsigned short v = __hip_atomic_load(&fl[lane], __ATOMIC_RELAXED,
                                             __HIP_MEMORY_SCOPE_AGENT);
        while (__ballot(v < tgt)) {
          __builtin_amdgcn_s_sleep(2);
          v = __hip_atomic_load(&fl[lane], __ATOMIC_RELAXED,
                                __HIP_MEMORY_SCOPE_AGENT);
        }
      }
      __syncthreads();   // release; orders next-step h loads + gbuf reuse
    }
  }
}

// ---------------------------------------------------------------------------
extern "C" void kernel_launch(void* const* d_in, const int* in_sizes, int n_in,
                              void* d_out, int out_size, void* d_ws, size_t ws_size,
                              hipStream_t stream) {
  const float* x   = (const float*)d_in[0];
  const float* wim = (const float*)d_in[1];
  const float* wir = (const float*)d_in[2];
  const float* wie = (const float*)d_in[3];
  const float* whm = (const float*)d_in[4];
  const float* whr = (const float*)d_in[5];
  const float* whe = (const float*)d_in[6];
  const float* bim = (const float*)d_in[7];
  const float* bir = (const float*)d_in[8];
  const float* bie = (const float*)d_in[9];
  const float* bhm = (const float*)d_in[10];
  const float* bhr = (const float*)d_in[11];
  const float* bhe = (const float*)d_in[12];
  char* ws = (char*)d_ws;
  unsigned short* Wg    = (unsigned short*)(ws + WS_WG);
  unsigned short* xbf   = (unsigned short*)(ws + WS_XBF);
  float*          bsum  = (float*)(ws + WS_BSUM);
  double*         accd  = (double*)(ws + WS_ACC);
  unsigned short* flags = (unsigned short*)(ws + WS_FLAGS);
  unsigned short* hbuf  = (unsigned short*)(ws + WS_HBUF);
  float* out = (float*)d_out;

  // epoch ring size: largest power-of-two slot count (<=16) that fits ws
  size_t avail = (ws_size > WS_HBUF) ? ws_size - WS_HBUF : (size_t)0;
  int P = 2;
  while (P < 16 && (size_t)(P * 2) * 4ull * 65536ull <= avail) P *= 2;

  hipMemsetAsync(ws + WS_ACC, 0, WS_ZERO_LEN, stream);
  prep_kernel<<<dim3(1024), dim3(256), 0, stream>>>(
      x, wim, wir, wie, whm, whr, whe, bim, bir, bie, bhm, bhr, bhe,
      Wg, xbf, bsum, accd);

  const unsigned short* Wg_c = Wg; const unsigned short* xbf_c = xbf;
  const float* bsum_c = bsum; const double* acc_c = accd;
  void* args[] = {(void*)&Wg_c, (void*)&xbf_c, (void*)&bsum_c,
                  (void*)&hbuf, (void*)&flags, (void*)&acc_c, (void*)&out,
                  (void*)&P};
  hipError_t e = hipLaunchCooperativeKernel((void*)lstm_kernel, dim3(256), dim3(256),
                                            args, 0u, stream);
  if (e != hipSuccess) {
    // fallback: 256 blocks / 256 CUs at 1 block/CU are co-resident in practice
    lstm_kernel<<<dim3(256), dim3(256), 0, stream>>>(Wg_c, xbf_c, bsum_c,
                                                     hbuf, flags, acc_c, out,
                                                     P);
  }
}